// Round 9
// baseline (338.986 us; speedup 1.0000x reference)
//
#include <hip/hip_runtime.h>
#include <math.h>

typedef unsigned short u16;
typedef __attribute__((ext_vector_type(8))) short short8;   // 8 bf16 operand frag (4 VGPRs)
typedef __attribute__((ext_vector_type(4))) float floatx4;  // 4 fp32 accum frag

#define LDS_AS(p) ((__attribute__((address_space(3))) void*)(p))
#define GLB_AS(p) ((const __attribute__((address_space(1))) void*)(p))

__device__ __forceinline__ u16 f2bf(float f) {
  unsigned int u = __float_as_uint(f);
  u += 0x7fffu + ((u >> 16) & 1u);          // round-to-nearest-even
  return (u16)(u >> 16);
}

__device__ __forceinline__ void gld16(const void* g, void* l) {
  // async global->LDS, 16B/lane, dest = wave-uniform base + lane*16
  __builtin_amdgcn_global_load_lds(GLB_AS(g), LDS_AS(l), 16, 0, 0);
}

__device__ __forceinline__ floatx4 mfma16(short8 a, short8 b, floatx4 c) {
  return __builtin_amdgcn_mfma_f32_16x16x32_bf16(a, b, c, 0, 0, 0);
}

// ---------------------------------------------------------------- fused prep
// __sincosf (fast intrinsic, no libm ABI call/stack frame) — the sincosf call
// was imposing a call-frame + caller-save spills on the whole fused kernel.
__global__ void prep_kernel(const float* __restrict__ x, const float* __restrict__ Wq,
                            const float* __restrict__ Wk, const float* __restrict__ Wv,
                            const float* __restrict__ Wo, u16* __restrict__ xbf,
                            u16* __restrict__ wqkv, u16* __restrict__ wo,
                            float2* __restrict__ rtab) {
  int i = blockIdx.x * blockDim.x + threadIdx.x;
  const int str = gridDim.x * blockDim.x;
  for (; i < 3211264; i += str) {
    if (i < 3145728) {
      const float* s; u16* d; int j;
      if (i < 2097152)      { s = x;  d = xbf;            j = i; }
      else if (i < 2359296) { s = Wq; d = wqkv;           j = i - 2097152; }
      else if (i < 2621440) { s = Wk; d = wqkv + 1048576; j = i - 2359296; }
      else if (i < 2883584) { s = Wv; d = wqkv + 2097152; j = i - 2621440; }
      else                  { s = Wo; d = wo;             j = i - 2883584; }
      float4 v = ((const float4*)s)[j];
      ushort4 o;
      o.x = f2bf(v.x); o.y = f2bf(v.y); o.z = f2bf(v.z); o.w = f2bf(v.w);
      ((ushort4*)d)[j] = o;
    } else {
      const int t = i - 3145728;              // 0..65535
      const int seq = t >> 5, dh = t & 31;
      const float freq = exp2f(-(float)dh * 0.42863594770f); // log2(1e4)/31
      float sn, cs;
      __sincosf((float)seq * freq, &sn, &cs);
      rtab[t] = make_float2(sn, cs);
    }
  }
}

// ---------------------------------------------------------------- GEMM C = A * B^T
// 128x128 tile, BK=64, fragment-ordered LDS K-loop (plateau for this family).
// EPI 0: outputs staged via LDS, full-128B-segment stores (round-8 fix).
// EPI 1: fp32 out ALSO staged via LDS now — old path stored 64 B half-line
// segments at 4 KB stride (RMW line allocation). Quarter-tile passes, pitch 65
// (<=2-way bank aliasing on readback = free).
template <int EPI>
__global__ __launch_bounds__(256, 2)
void gemm_bt(const u16* __restrict__ A, const u16* __restrict__ Bw, int K,
             u16* __restrict__ qb, u16* __restrict__ kb, u16* __restrict__ vtb,
             u16* __restrict__ kwt, const float2* __restrict__ rtab,
             float* __restrict__ outp) {
  __shared__ __align__(16) u16 Asm[16 * 512];   // 8 row-tiles x 2 k-halves
  __shared__ __align__(16) u16 Bsm[16 * 512];
  const int tid = threadIdx.x;
  const int w = tid >> 6, lane = tid & 63;
  const int quad = lane >> 4, l15 = lane & 15;
  const int m0 = blockIdx.y * 128, n0 = blockIdx.x * 128;

  // staging: wave w stages A row-tiles {2w,2w+1}, both 32-wide k-halves
  const u16* Ag = A + (size_t)(m0 + (2 * w) * 16 + l15) * K + quad * 8;
  const u16* Bg = Bw + (size_t)(n0 + (2 * w) * 16 + l15) * K + quad * 8;
  const size_t row16 = (size_t)16 * K;

  const u16* Apane = &Asm[(w & 1) * 8 * 512];   // 4 row-tiles x 2 kk
  const u16* Bpane = &Bsm[(w >> 1) * 8 * 512];

  floatx4 acc[4][4] = {};

  for (int k0 = 0; k0 < K; k0 += 64) {
#pragma unroll
    for (int rt = 0; rt < 2; ++rt)
#pragma unroll
      for (int kk = 0; kk < 2; ++kk) {
        gld16(Ag + rt * row16 + k0 + kk * 32, &Asm[((2 * w + rt) * 2 + kk) * 512]);
        gld16(Bg + rt * row16 + k0 + kk * 32, &Bsm[((2 * w + rt) * 2 + kk) * 512]);
      }
    __syncthreads();   // drains vmcnt: staging complete
#pragma unroll
    for (int kk = 0; kk < 2; ++kk) {
      short8 a[4], b[4];
#pragma unroll
      for (int i = 0; i < 4; ++i)
        a[i] = *(const short8*)&Apane[(i * 2 + kk) * 512 + lane * 8];
#pragma unroll
      for (int j = 0; j < 4; ++j)
        b[j] = *(const short8*)&Bpane[(j * 2 + kk) * 512 + lane * 8];
#pragma unroll
      for (int i = 0; i < 4; ++i)
#pragma unroll
        for (int j = 0; j < 4; ++j)
          acc[i][j] = mfma16(a[i], b[j], acc[i][j]);
    }
    __syncthreads();   // all waves done reading before next stage overwrites
  }
  // after the final barrier Asm/Bsm are dead -> 8 KB wave-private scratch
  u16* scr = (w < 2 ? Asm : Bsm) + (w & 1) * 4096;

  const int mrb = m0 + (w & 1) * 64;
  const int ncb = n0 + (w >> 1) * 64;

  if (EPI == 0) {
    const int which = n0 >> 10;       // 0:q 1:k 2:v
    const int c1024 = ncb & 1023;
    const int bidx = mrb >> 11;
    const int hh = c1024 >> 6;        // wave-tile = one full head (64 d)
    const int seq0 = mrb & 2047;
    const int lr = lane >> 3, lc = lane & 7;   // readback row-group / 16B chunk

    if (which < 2) {
      // ---- pass 1: plain q/k [bh][s][64], RoPE applied
#pragma unroll
      for (int j = 0; j < 4; ++j) {
        const int d = j * 16 + l15;
#pragma unroll
        for (int i = 0; i < 4; ++i)
#pragma unroll
          for (int r = 0; r < 4; ++r) {
            const int sl = i * 16 + quad * 4 + r;
            const int seq = seq0 + sl;
            const float v = acc[i][j][r];
            const float p = __shfl_xor(v, 1, 64);
            const float2 sc = rtab[(d >> 1) + seq * 32];
            const float res = (d & 1) ? (v * sc.y + p * sc.x) : (v * sc.y - p * sc.x);
            scr[sl * 64 + d] = f2bf(res);        // LDS tile [seq_l][d]
          }
      }
      u16* dst = ((which == 0) ? qb : kb) + (size_t)(bidx * 16 + hh) * 131072 +
                 (size_t)seq0 * 64;
#pragma unroll
      for (int cch = 0; cch < 8; ++cch) {        // 8 stores, 8x128B segments each
        const int row = cch * 8 + lr;
        short8 vv = *(const short8*)&scr[row * 64 + lc * 8];
        *(short8*)(dst + (size_t)row * 64 + lc * 8) = vv;
      }
      if (which == 1) {
        // ---- pass 2: kwt [bh][dk][t], decay-weighted, transposed via LDS
        const float l2h = __log2f(1.0f - exp2f(-(float)(5 + hh)));
#pragma unroll
        for (int j = 0; j < 4; ++j) {
          const int d = j * 16 + l15;
#pragma unroll
          for (int i = 0; i < 4; ++i) {
            ushort4 pk;
#pragma unroll
            for (int r = 0; r < 4; ++r) {
              const int sl = i * 16 + quad * 4 + r;
              const int seq = seq0 + sl;
              const float v = acc[i][j][r];
              const float p = __shfl_xor(v, 1, 64);
              const float2 sc = rtab[(d >> 1) + seq * 32];
              const float res = (d & 1) ? (v * sc.y + p * sc.x) : (v * sc.y - p * sc.x);
              const float wgt = exp2f((float)(127 - (seq & 127)) * l2h);
              ((u16*)&pk)[r] = f2bf(res * wgt);
            }
            *(ushort4*)&scr[d * 64 + i * 16 + quad * 4] = pk;   // tile [d][seq_l]
          }
        }
        u16* dw = kwt + (size_t)(bidx * 16 + hh) * 131072 + seq0;
#pragma unroll
        for (int cch = 0; cch < 8; ++cch) {
          const int drow = cch * 8 + lr;
          short8 vv = *(const short8*)&scr[drow * 64 + lc * 8];
          *(short8*)(dw + (size_t)drow * 2048 + lc * 8) = vv;
        }
      }
    } else {
      // ---- v transposed [bh][d][s] via LDS
#pragma unroll
      for (int j = 0; j < 4; ++j) {
        const int d = j * 16 + l15;
#pragma unroll
        for (int i = 0; i < 4; ++i) {
          ushort4 pk;
          pk.x = f2bf(acc[i][j][0]);
          pk.y = f2bf(acc[i][j][1]);
          pk.z = f2bf(acc[i][j][2]);
          pk.w = f2bf(acc[i][j][3]);
          *(ushort4*)&scr[d * 64 + i * 16 + quad * 4] = pk;     // tile [d][seq_l]
        }
      }
      u16* dh = vtb + (size_t)(bidx * 16 + hh) * 131072 + seq0;
#pragma unroll
      for (int cch = 0; cch < 8; ++cch) {
        const int drow = cch * 8 + lr;
        short8 vv = *(const short8*)&scr[drow * 64 + lc * 8];
        *(short8*)(dh + (size_t)drow * 2048 + lc * 8) = vv;
      }
    }
  } else {
    // ---- fp32 out via LDS quarter-tiles (16 rows x pitch 65), full-line stores
    float* scrf = (float*)scr;                  // 8 KB = 2048 fp32
    const int lr4 = lane >> 4, lc16 = lane & 15;
#pragma unroll
    for (int p = 0; p < 4; ++p) {               // p = row-group (acc i index)
#pragma unroll
      for (int j = 0; j < 4; ++j)
#pragma unroll
        for (int r = 0; r < 4; ++r)
          scrf[(quad * 4 + r) * 65 + j * 16 + l15] = acc[p][j][r];
#pragma unroll
      for (int cch = 0; cch < 4; ++cch) {       // 4 stores x 4 rows x 256 B
        const int rr = cch * 4 + lr4;
        float4 vv = *(const float4*)&scrf[rr * 65 + lc16 * 4];
        *(float4*)&outp[(size_t)(mrb + p * 16 + rr) * 1024 + ncb + lc16 * 4] = vv;
      }
    }
  }
}

// ---------------------------------------------------------------- chunk KV: U_c = sum_t w_t k_t v_t^T
__global__ __launch_bounds__(256, 4)
void kvchunk_kernel(const u16* __restrict__ kwt, const u16* __restrict__ vtb,
                    float* __restrict__ U) {
  __shared__ __align__(16) u16 kls[16 * 512];
  __shared__ __align__(16) u16 vls[16 * 512];
  const int c = blockIdx.x, bh = blockIdx.y;
  const int tid = threadIdx.x, w = tid >> 6, lane = tid & 63;
  const int quad = lane >> 4, l15 = lane & 15;
  const u16* kg = kwt + (size_t)bh * 131072 + c * 128;
  const u16* vg = vtb + (size_t)bh * 131072 + c * 128;
#pragma unroll
  for (int rg = 0; rg < 4; ++rg) {
    const int rid = w * 4 + rg;               // 16 regions: (tile m, kst)
    const int m = rid >> 2, kst = rid & 3;
    gld16(kg + (size_t)(m * 16 + l15) * 2048 + kst * 32 + quad * 8, &kls[rid * 512]);
    gld16(vg + (size_t)(m * 16 + l15) * 2048 + kst * 32 + quad * 8, &vls[rid * 512]);
  }
  __syncthreads();
  floatx4 acc[4] = {};
#pragma unroll
  for (int kst = 0; kst < 4; ++kst) {
    short8 bf = *(const short8*)&vls[(w * 4 + kst) * 512 + lane * 8];
#pragma unroll
    for (int m = 0; m < 4; ++m) {
      short8 af = *(const short8*)&kls[(m * 4 + kst) * 512 + lane * 8];
      acc[m] = mfma16(af, bf, acc[m]);
    }
  }
  float* Ub = U + ((size_t)bh * 16 + c) * 4096;
#pragma unroll
  for (int m = 0; m < 4; ++m)
#pragma unroll
    for (int r = 0; r < 4; ++r)
      Ub[(m * 16 + quad * 4 + r) * 64 + w * 16 + l15] = acc[m][r];
}

// ---------------------------------------------------------------- state scan
__global__ void scan_kernel(const float* __restrict__ U, u16* __restrict__ Sb) {
  const int bh = blockIdx.x, l = threadIdx.x;
  const int h = bh & 15;
  const float l2 = __log2f(1.0f - exp2f(-(float)(5 + h)));
  const float lamL = exp2f(128.0f * l2);
  float S[64];
#pragma unroll
  for (int i = 0; i < 64; ++i) S[i] = 0.f;
  for (int c = 0; c < 16; ++c) {
    u16* sp = Sb + ((size_t)bh * 16 + c) * 4096 + l * 64;
#pragma unroll 8
    for (int dk = 0; dk < 64; dk += 4) {
      ushort4 pk;
      pk.x = f2bf(S[dk]);     pk.y = f2bf(S[dk + 1]);
      pk.z = f2bf(S[dk + 2]); pk.w = f2bf(S[dk + 3]);
      *(ushort4*)&sp[dk] = pk;
    }
    const float* up = U + ((size_t)bh * 16 + c) * 4096 + l;
#pragma unroll 8
    for (int dk = 0; dk < 64; ++dk)
      S[dk] = lamL * S[dk] + up[dk * 64];
  }
}

// ---------------------------------------------------------------- chunked attention
__global__ __launch_bounds__(256, 2)
void attn_chunk_kernel(const u16* __restrict__ qb, const u16* __restrict__ kb,
                       const u16* __restrict__ vtb, const u16* __restrict__ Sb,
                       const float* __restrict__ lnw, const float* __restrict__ lnb,
                       u16* __restrict__ yb) {
  __shared__ __align__(16) u16 kls[16 * 512];
  __shared__ __align__(16) u16 vls[16 * 512];
  __shared__ __align__(16) u16 Sls[8 * 512];
  __shared__ __align__(16) u16 pls[4 * 32 * 40];   // per-wave quarter P strip, pitch 40

  const int c = blockIdx.x, bh = blockIdx.y, h = bh & 15;
  const int tid = threadIdx.x;
  const int w = tid >> 6, lane = tid & 63, quad = lane >> 4, l15 = lane & 15;
  const float l2 = __log2f(1.0f - exp2f(-(float)(5 + h)));

  const u16* kg = kb + (size_t)bh * 131072 + (size_t)c * 128 * 64;
  const u16* vg = vtb + (size_t)bh * 131072 + c * 128;
  const u16* Sg = Sb + ((size_t)bh * 16 + c) * 4096;
#pragma unroll
  for (int rg = 0; rg < 4; ++rg) {
    const int kid = w * 4 + rg;
    const int nsub = kid >> 1, kk = kid & 1;     // k regions (t-tile, d-half)
    gld16(kg + (size_t)(nsub * 16 + l15) * 64 + kk * 32 + quad * 8, &kls[kid * 512]);
    const int jd = kid >> 2, kst = kid & 3;      // v regions (d-tile, t-step)
    gld16(vg + (size_t)(jd * 16 + l15) * 2048 + kst * 32 + quad * 8, &vls[kid * 512]);
  }
#pragma unroll
  for (int e = 0; e < 2; ++e) {
    const int rid = w * 2 + e;                   // S regions (dv-tile, dk-half)
    const int nd = rid >> 1, kk = rid & 1;
    gld16(Sg + (size_t)(nd * 16 + l15) * 64 + kk * 32 + quad * 8, &Sls[rid * 512]);
  }

  // q fragments (global loads, not part of LDS staging)
  short8 qf[2][2];
  {
    const u16* qbase = qb + ((size_t)bh * 2048 + c * 128 + w * 32 + l15) * 64 + quad * 8;
#pragma unroll
    for (int i = 0; i < 2; ++i)
#pragma unroll
      for (int kk = 0; kk < 2; ++kk)
        qf[i][kk] = *(const short8*)(qbase + (size_t)i * 16 * 64 + kk * 32);
  }
  float lnwv[4], lnbv[4];
#pragma unroll
  for (int jd = 0; jd < 4; ++jd) {
    lnwv[jd] = lnw[jd * 16 + l15];
    lnbv[jd] = lnb[jd * 16 + l15];
  }
  __syncthreads();

  // ---- intra scores: S = q k^T (32 s-rows x 128 t-cols)
  floatx4 sacc[2][8] = {};
#pragma unroll
  for (int kk = 0; kk < 2; ++kk) {
    short8 bf[8];
#pragma unroll
    for (int j = 0; j < 8; ++j)
      bf[j] = *(const short8*)&kls[(j * 2 + kk) * 512 + lane * 8];
#pragma unroll
    for (int i = 0; i < 2; ++i)
#pragma unroll
      for (int j = 0; j < 8; ++j)
        sacc[i][j] = mfma16(qf[i][kk], bf[j], sacc[i][j]);
  }

  // ---- cross: oacc = q . S_state^T, scaled by lambda^{s_loc+1}
  floatx4 oacc[2][4] = {};
#pragma unroll
  for (int kk = 0; kk < 2; ++kk)
#pragma unroll
    for (int nd = 0; nd < 4; ++nd) {
      short8 sf = *(const short8*)&Sls[(nd * 2 + kk) * 512 + lane * 8];
#pragma unroll
      for (int i = 0; i < 2; ++i)
        oacc[i][nd] = mfma16(qf[i][kk], sf, oacc[i][nd]);
    }
  float rowf[8];
#pragma unroll
  for (int i = 0; i < 2; ++i)
#pragma unroll
    for (int r = 0; r < 4; ++r)
      rowf[i * 4 + r] = exp2f((float)(w * 32 + i * 16 + quad * 4 + r) * l2);
  const float lam1 = exp2f(l2);
#pragma unroll
  for (int i = 0; i < 2; ++i)
#pragma unroll
    for (int nd = 0; nd < 4; ++nd)
#pragma unroll
      for (int r = 0; r < 4; ++r)
        oacc[i][nd][r] *= rowf[i * 4 + r] * lam1;   // lambda^{s_loc+1}

  // ---- intra PV with masked/decayed P, quarter-strip at a time
  float colf[8];
#pragma unroll
  for (int j = 0; j < 8; ++j) colf[j] = exp2f(-(float)(j * 16 + l15) * l2);
  u16* pw = &pls[w * 1280];
#pragma unroll
  for (int kst = 0; kst < 4; ++kst) {
#pragma unroll
    for (int jl = 0; jl < 2; ++jl) {
      const int j = kst * 2 + jl;
#pragma unroll
      for (int i = 0; i < 2; ++i)
#pragma unroll
        for (int r = 0; r < 4; ++r) {
          const int srow = i * 16 + quad * 4 + r;            // wave-local s
          const int dlt = (w * 32 + srow) - (j * 16 + l15);  // causal in-chunk
          const float v =
              (dlt >= 0) ? sacc[i][j][r] * rowf[i * 4 + r] * colf[j] : 0.0f;
          pw[srow * 40 + jl * 16 + l15] = f2bf(v);
        }
    }
    short8 pf[2], vf[4];
#pragma unroll
    for (int i = 0; i < 2; ++i)
      pf[i] = *(const short8*)&pw[(i * 16 + l15) * 40 + quad * 8];
#pragma unroll
    for (int jd = 0; jd < 4; ++jd)
      vf[jd] = *(const short8*)&vls[(jd * 4 + kst) * 512 + lane * 8];
#pragma unroll
    for (int i = 0; i < 2; ++i)
#pragma unroll
      for (int jd = 0; jd < 4; ++jd)
        oacc[i][jd] = mfma16(pf[i], vf[jd], oacc[i][jd]);
  }

  // ---- LayerNorm(64) + SiLU -> y bf16 [token][h*64+d]
  const int b = bh >> 4;
#pragma unroll
  for (int i = 0; i < 2; ++i)
#pragma unroll
    for (int r = 0; r < 4; ++r) {
      float sum = 0.f, ssq = 0.f;
#pragma unroll
      for (int jd = 0; jd < 4; ++jd) {
        const float v = oacc[i][jd][r];
        sum += v;
        ssq += v * v;
      }
#pragma unroll
      for (int off = 1; off < 16; off <<= 1) {
        sum += __shfl_xor(sum, off, 64);
        ssq += __shfl_xor(ssq, off, 64);
      }
      const float mu = sum * (1.0f / 64.0f);
      const float var = ssq * (1.0f / 64.0f) - mu * mu;
      const float rst = rsqrtf(var + 1e-5f);
      const int sg = c * 128 + w * 32 + i * 16 + quad * 4 + r;
      u16* dst = yb + ((size_t)b * 2048 + sg) * 1024 + h * 64;
#pragma unroll
      for (int jd = 0; jd < 4; ++jd) {
        const float z = (oacc[i][jd][r] - mu) * rst * lnwv[jd] + lnbv[jd];
        const float y = z / (1.0f + expf(-z));   // SiLU
        dst[jd * 16 + l15] = f2bf(y);
      }
    }
}

// ---------------------------------------------------------------- launch
extern "C" void kernel_launch(void* const* d_in, const int* in_sizes, int n_in,
                              void* d_out, int out_size, void* d_ws, size_t ws_size,
                              hipStream_t stream) {
  const float* x   = (const float*)d_in[0];
  const float* Wq  = (const float*)d_in[1];
  const float* Wk  = (const float*)d_in[2];
  const float* Wv  = (const float*)d_in[3];
  const float* Wo  = (const float*)d_in[4];
  const float* lnw = (const float*)d_in[5];
  const float* lnb = (const float*)d_in[6];
  float* out = (float*)d_out;

  char* ws = (char*)d_ws;
  u16* xbf  = (u16*)(ws + 0);         // 16 MB (8192x1024 bf16), reused as y
  u16* wqkv = (u16*)(ws + 16777216);  // 6 MB — dead after QKV gemm
  u16* Sb   = (u16*)(ws + 16777216);  // 8 MB S^T states — written after wqkv dead
  u16* qbuf = (u16*)(ws + 25165824);  // 16 MB [bh][s][64]
  u16* kbuf = (u16*)(ws + 41943040);  // 16 MB [bh][s][64]
  u16* vtb  = (u16*)(ws + 58720256);  // 16 MB [bh][64][s]
  u16* wo   = (u16*)(ws + 75497472);  // 2 MB
  float2* rtab = (float2*)(ws + 77594624);  // 512 KB
  u16* yb   = xbf;
  // d_out doubles as scratch until the final GEMM overwrites it entirely:
  u16* kwt  = (u16*)d_out;                          // 16 MB [bh][dk][t] weighted k^T
  float* Ubuf = (float*)((char*)d_out + 16777216);  // 16 MB fp32 chunk outer products

  prep_kernel<<<dim3(1024), dim3(256), 0, stream>>>(x, Wq, Wk, Wv, Wo, xbf, wqkv, wo,
                                                    rtab);
  gemm_bt<0><<<dim3(24, 64), dim3(256), 0, stream>>>(xbf, wqkv, 1024, qbuf, kbuf, vtb,
                                                     kwt, rtab, nullptr);
  kvchunk_kernel<<<dim3(16, 64), dim3(256), 0, stream>>>(kwt, vtb, Ubuf);
  scan_kernel<<<dim3(64), dim3(64), 0, stream>>>(Ubuf, Sb);
  attn_chunk_kernel<<<dim3(16, 64), dim3(256), 0, stream>>>(qbuf, kbuf, vtb, Sb, lnw,
                                                            lnb, yb);
  gemm_bt<1><<<dim3(8, 64), dim3(256), 0, stream>>>(yb, wo, 1024, nullptr, nullptr,
                                                    nullptr, nullptr, nullptr, out);
}

// Round 10
// 315.584 us; speedup vs baseline: 1.0742x; 1.0742x over previous
//
#include <hip/hip_runtime.h>
#include <math.h>

typedef unsigned short u16;
typedef __attribute__((ext_vector_type(8))) short short8;   // 8 bf16 operand frag (4 VGPRs)
typedef __attribute__((ext_vector_type(4))) float floatx4;  // 4 fp32 accum frag

#define LDS_AS(p) ((__attribute__((address_space(3))) void*)(p))
#define GLB_AS(p) ((const __attribute__((address_space(1))) void*)(p))

__device__ __forceinline__ u16 f2bf(float f) {
  unsigned int u = __float_as_uint(f);
  u += 0x7fffu + ((u >> 16) & 1u);          // round-to-nearest-even
  return (u16)(u >> 16);
}

__device__ __forceinline__ void gld16(const void* g, void* l) {
  // async global->LDS, 16B/lane, dest = wave-uniform base + lane*16
  __builtin_amdgcn_global_load_lds(GLB_AS(g), LDS_AS(l), 16, 0, 0);
}

__device__ __forceinline__ floatx4 mfma16(short8 a, short8 b, floatx4 c) {
  return __builtin_amdgcn_mfma_f32_16x16x32_bf16(a, b, c, 0, 0, 0);
}

// ---------------------------------------------------------------- fused prep
__global__ void prep_kernel(const float* __restrict__ x, const float* __restrict__ Wq,
                            const float* __restrict__ Wk, const float* __restrict__ Wv,
                            const float* __restrict__ Wo, u16* __restrict__ xbf,
                            u16* __restrict__ wqkv, u16* __restrict__ wo,
                            float2* __restrict__ rtab) {
  int i = blockIdx.x * blockDim.x + threadIdx.x;
  const int str = gridDim.x * blockDim.x;
  for (; i < 3211264; i += str) {
    if (i < 3145728) {
      const float* s; u16* d; int j;
      if (i < 2097152)      { s = x;  d = xbf;            j = i; }
      else if (i < 2359296) { s = Wq; d = wqkv;           j = i - 2097152; }
      else if (i < 2621440) { s = Wk; d = wqkv + 1048576; j = i - 2359296; }
      else if (i < 2883584) { s = Wv; d = wqkv + 2097152; j = i - 2621440; }
      else                  { s = Wo; d = wo;             j = i - 2883584; }
      float4 v = ((const float4*)s)[j];
      ushort4 o;
      o.x = f2bf(v.x); o.y = f2bf(v.y); o.z = f2bf(v.z); o.w = f2bf(v.w);
      ((ushort4*)d)[j] = o;
    } else {
      const int t = i - 3145728;              // 0..65535
      const int seq = t >> 5, dh = t & 31;
      const float freq = exp2f(-(float)dh * 0.42863594770f); // log2(1e4)/31
      float sn, cs;
      __sincosf((float)seq * freq, &sn, &cs);
      rtab[t] = make_float2(sn, cs);
    }
  }
}

// ---------------------------------------------------------------- GEMM C = A * B^T
// 128x128 tile, BK=64, fragment-ordered LDS K-loop.
// XCD-AWARE SWIZZLE: observed 38 B/cyc/CU staging throughput = Little's-law
// latency bound (A+B working set cycles through per-XCD L2 because consecutive
// blocks land on different XCDs). Remap so XCD j (block lin id % 8) permanently
// owns a fixed set of n-tiles: its B slab (768 KB for EPI0, 256 KB for EPI1)
// stays hot in its 4 MB L2, and the current A slab (256 KB, shared by the
// XCD's consecutive blocks) is hot too -> L2-hit latency, higher throughput.
// EPI 0: outputs staged via LDS, full-128B-segment stores. EPI 1: fp32 out
// via LDS quarter-tiles.
template <int EPI>
__global__ __launch_bounds__(256, 2)
void gemm_bt(const u16* __restrict__ A, const u16* __restrict__ Bw, int K,
             u16* __restrict__ qb, u16* __restrict__ kb, u16* __restrict__ vtb,
             u16* __restrict__ kwt, const float2* __restrict__ rtab,
             float* __restrict__ outp) {
  __shared__ __align__(16) u16 Asm[16 * 512];   // 8 row-tiles x 2 k-halves
  __shared__ __align__(16) u16 Bsm[16 * 512];
  const int tid = threadIdx.x;
  const int w = tid >> 6, lane = tid & 63;
  const int quad = lane >> 4, l15 = lane & 15;

  // bijective XCD-locality remap (exact: 24 and 8 are both ≡0 mod 8)
  int ntile, mtile;
  if (EPI == 0) {
    const int bl = blockIdx.x + 24 * blockIdx.y;     // grid (24,64)
    ntile = 3 * (bl & 7) + ((bl >> 3) % 3);          // XCD j -> n-tiles {3j..3j+2}
    mtile = bl / 24;
  } else {
    const int bl = blockIdx.x + 8 * blockIdx.y;      // grid (8,64)
    ntile = bl & 7;                                  // XCD j -> n-tile j
    mtile = bl >> 3;
  }
  const int m0 = mtile * 128, n0 = ntile * 128;

  // staging: wave w stages A row-tiles {2w,2w+1}, both 32-wide k-halves
  const u16* Ag = A + (size_t)(m0 + (2 * w) * 16 + l15) * K + quad * 8;
  const u16* Bg = Bw + (size_t)(n0 + (2 * w) * 16 + l15) * K + quad * 8;
  const size_t row16 = (size_t)16 * K;

  const u16* Apane = &Asm[(w & 1) * 8 * 512];   // 4 row-tiles x 2 kk
  const u16* Bpane = &Bsm[(w >> 1) * 8 * 512];

  floatx4 acc[4][4] = {};

  for (int k0 = 0; k0 < K; k0 += 64) {
#pragma unroll
    for (int rt = 0; rt < 2; ++rt)
#pragma unroll
      for (int kk = 0; kk < 2; ++kk) {
        gld16(Ag + rt * row16 + k0 + kk * 32, &Asm[((2 * w + rt) * 2 + kk) * 512]);
        gld16(Bg + rt * row16 + k0 + kk * 32, &Bsm[((2 * w + rt) * 2 + kk) * 512]);
      }
    __syncthreads();   // drains vmcnt: staging complete
#pragma unroll
    for (int kk = 0; kk < 2; ++kk) {
      short8 a[4], b[4];
#pragma unroll
      for (int i = 0; i < 4; ++i)
        a[i] = *(const short8*)&Apane[(i * 2 + kk) * 512 + lane * 8];
#pragma unroll
      for (int j = 0; j < 4; ++j)
        b[j] = *(const short8*)&Bpane[(j * 2 + kk) * 512 + lane * 8];
#pragma unroll
      for (int i = 0; i < 4; ++i)
#pragma unroll
        for (int j = 0; j < 4; ++j)
          acc[i][j] = mfma16(a[i], b[j], acc[i][j]);
    }
    __syncthreads();   // all waves done reading before next stage overwrites
  }
  // after the final barrier Asm/Bsm are dead -> 8 KB wave-private scratch
  u16* scr = (w < 2 ? Asm : Bsm) + (w & 1) * 4096;

  const int mrb = m0 + (w & 1) * 64;
  const int ncb = n0 + (w >> 1) * 64;

  if (EPI == 0) {
    const int which = n0 >> 10;       // 0:q 1:k 2:v
    const int c1024 = ncb & 1023;
    const int bidx = mrb >> 11;
    const int hh = c1024 >> 6;        // wave-tile = one full head (64 d)
    const int seq0 = mrb & 2047;
    const int lr = lane >> 3, lc = lane & 7;   // readback row-group / 16B chunk

    if (which < 2) {
      // ---- pass 1: plain q/k [bh][s][64], RoPE applied
#pragma unroll
      for (int j = 0; j < 4; ++j) {
        const int d = j * 16 + l15;
#pragma unroll
        for (int i = 0; i < 4; ++i)
#pragma unroll
          for (int r = 0; r < 4; ++r) {
            const int sl = i * 16 + quad * 4 + r;
            const int seq = seq0 + sl;
            const float v = acc[i][j][r];
            const float p = __shfl_xor(v, 1, 64);
            const float2 sc = rtab[(d >> 1) + seq * 32];
            const float res = (d & 1) ? (v * sc.y + p * sc.x) : (v * sc.y - p * sc.x);
            scr[sl * 64 + d] = f2bf(res);        // LDS tile [seq_l][d]
          }
      }
      u16* dst = ((which == 0) ? qb : kb) + (size_t)(bidx * 16 + hh) * 131072 +
                 (size_t)seq0 * 64;
#pragma unroll
      for (int cch = 0; cch < 8; ++cch) {        // 8 stores, 8x128B segments each
        const int row = cch * 8 + lr;
        short8 vv = *(const short8*)&scr[row * 64 + lc * 8];
        *(short8*)(dst + (size_t)row * 64 + lc * 8) = vv;
      }
      if (which == 1) {
        // ---- pass 2: kwt [bh][dk][t], decay-weighted, transposed via LDS
        const float l2h = __log2f(1.0f - exp2f(-(float)(5 + hh)));
#pragma unroll
        for (int j = 0; j < 4; ++j) {
          const int d = j * 16 + l15;
#pragma unroll
          for (int i = 0; i < 4; ++i) {
            ushort4 pk;
#pragma unroll
            for (int r = 0; r < 4; ++r) {
              const int sl = i * 16 + quad * 4 + r;
              const int seq = seq0 + sl;
              const float v = acc[i][j][r];
              const float p = __shfl_xor(v, 1, 64);
              const float2 sc = rtab[(d >> 1) + seq * 32];
              const float res = (d & 1) ? (v * sc.y + p * sc.x) : (v * sc.y - p * sc.x);
              const float wgt = exp2f((float)(127 - (seq & 127)) * l2h);
              ((u16*)&pk)[r] = f2bf(res * wgt);
            }
            *(ushort4*)&scr[d * 64 + i * 16 + quad * 4] = pk;   // tile [d][seq_l]
          }
        }
        u16* dw = kwt + (size_t)(bidx * 16 + hh) * 131072 + seq0;
#pragma unroll
        for (int cch = 0; cch < 8; ++cch) {
          const int drow = cch * 8 + lr;
          short8 vv = *(const short8*)&scr[drow * 64 + lc * 8];
          *(short8*)(dw + (size_t)drow * 2048 + lc * 8) = vv;
        }
      }
    } else {
      // ---- v transposed [bh][d][s] via LDS
#pragma unroll
      for (int j = 0; j < 4; ++j) {
        const int d = j * 16 + l15;
#pragma unroll
        for (int i = 0; i < 4; ++i) {
          ushort4 pk;
          pk.x = f2bf(acc[i][j][0]);
          pk.y = f2bf(acc[i][j][1]);
          pk.z = f2bf(acc[i][j][2]);
          pk.w = f2bf(acc[i][j][3]);
          *(ushort4*)&scr[d * 64 + i * 16 + quad * 4] = pk;     // tile [d][seq_l]
        }
      }
      u16* dh = vtb + (size_t)(bidx * 16 + hh) * 131072 + seq0;
#pragma unroll
      for (int cch = 0; cch < 8; ++cch) {
        const int drow = cch * 8 + lr;
        short8 vv = *(const short8*)&scr[drow * 64 + lc * 8];
        *(short8*)(dh + (size_t)drow * 2048 + lc * 8) = vv;
      }
    }
  } else {
    // ---- fp32 out via LDS quarter-tiles (16 rows x pitch 65), full-line stores
    float* scrf = (float*)scr;                  // 8 KB = 2048 fp32
    const int lr4 = lane >> 4, lc16 = lane & 15;
#pragma unroll
    for (int p = 0; p < 4; ++p) {               // p = row-group (acc i index)
#pragma unroll
      for (int j = 0; j < 4; ++j)
#pragma unroll
        for (int r = 0; r < 4; ++r)
          scrf[(quad * 4 + r) * 65 + j * 16 + l15] = acc[p][j][r];
#pragma unroll
      for (int cch = 0; cch < 4; ++cch) {       // 4 stores x 4 rows x 256 B
        const int rr = cch * 4 + lr4;
        float4 vv = *(const float4*)&scrf[rr * 65 + lc16 * 4];
        *(float4*)&outp[(size_t)(mrb + p * 16 + rr) * 1024 + ncb + lc16 * 4] = vv;
      }
    }
  }
}

// ---------------------------------------------------------------- chunk KV: U_c = sum_t w_t k_t v_t^T
__global__ __launch_bounds__(256, 4)
void kvchunk_kernel(const u16* __restrict__ kwt, const u16* __restrict__ vtb,
                    float* __restrict__ U) {
  __shared__ __align__(16) u16 kls[16 * 512];
  __shared__ __align__(16) u16 vls[16 * 512];
  const int c = blockIdx.x, bh = blockIdx.y;
  const int tid = threadIdx.x, w = tid >> 6, lane = tid & 63;
  const int quad = lane >> 4, l15 = lane & 15;
  const u16* kg = kwt + (size_t)bh * 131072 + c * 128;
  const u16* vg = vtb + (size_t)bh * 131072 + c * 128;
#pragma unroll
  for (int rg = 0; rg < 4; ++rg) {
    const int rid = w * 4 + rg;               // 16 regions: (tile m, kst)
    const int m = rid >> 2, kst = rid & 3;
    gld16(kg + (size_t)(m * 16 + l15) * 2048 + kst * 32 + quad * 8, &kls[rid * 512]);
    gld16(vg + (size_t)(m * 16 + l15) * 2048 + kst * 32 + quad * 8, &vls[rid * 512]);
  }
  __syncthreads();
  floatx4 acc[4] = {};
#pragma unroll
  for (int kst = 0; kst < 4; ++kst) {
    short8 bf = *(const short8*)&vls[(w * 4 + kst) * 512 + lane * 8];
#pragma unroll
    for (int m = 0; m < 4; ++m) {
      short8 af = *(const short8*)&kls[(m * 4 + kst) * 512 + lane * 8];
      acc[m] = mfma16(af, bf, acc[m]);
    }
  }
  float* Ub = U + ((size_t)bh * 16 + c) * 4096;
#pragma unroll
  for (int m = 0; m < 4; ++m)
#pragma unroll
    for (int r = 0; r < 4; ++r)
      Ub[(m * 16 + quad * 4 + r) * 64 + w * 16 + l15] = acc[m][r];
}

// ---------------------------------------------------------------- state scan
// 64 blocks x 4 waves: wave w owns dk-quarter [w*16, w*16+16), lane = dv.
// S[dk][dv] recurrence is independent per element -> 4x the parallelism of
// the old 1-wave version (which ran 4096 threads on a 256-CU chip).
__global__ void scan_kernel(const float* __restrict__ U, u16* __restrict__ Sb) {
  const int bh = blockIdx.x;
  const int w = threadIdx.x >> 6, l = threadIdx.x & 63;
  const int h = bh & 15;
  const float l2 = __log2f(1.0f - exp2f(-(float)(5 + h)));
  const float lamL = exp2f(128.0f * l2);
  float S[16];
#pragma unroll
  for (int i = 0; i < 16; ++i) S[i] = 0.f;
  for (int c = 0; c < 16; ++c) {
    u16* sp = Sb + ((size_t)bh * 16 + c) * 4096 + l * 64 + w * 16;
#pragma unroll
    for (int dk = 0; dk < 16; dk += 4) {
      ushort4 pk;
      pk.x = f2bf(S[dk]);     pk.y = f2bf(S[dk + 1]);
      pk.z = f2bf(S[dk + 2]); pk.w = f2bf(S[dk + 3]);
      *(ushort4*)&sp[dk] = pk;
    }
    const float* up = U + ((size_t)bh * 16 + c) * 4096 + (w * 16) * 64 + l;
#pragma unroll
    for (int dk = 0; dk < 16; ++dk)
      S[dk] = lamL * S[dk] + up[dk * 64];
  }
}

// ---------------------------------------------------------------- chunked attention
__global__ __launch_bounds__(256, 2)
void attn_chunk_kernel(const u16* __restrict__ qb, const u16* __restrict__ kb,
                       const u16* __restrict__ vtb, const u16* __restrict__ Sb,
                       const float* __restrict__ lnw, const float* __restrict__ lnb,
                       u16* __restrict__ yb) {
  __shared__ __align__(16) u16 kls[16 * 512];
  __shared__ __align__(16) u16 vls[16 * 512];
  __shared__ __align__(16) u16 Sls[8 * 512];
  __shared__ __align__(16) u16 pls[4 * 32 * 40];   // per-wave quarter P strip, pitch 40

  const int c = blockIdx.x, bh = blockIdx.y, h = bh & 15;
  const int tid = threadIdx.x;
  const int w = tid >> 6, lane = tid & 63, quad = lane >> 4, l15 = lane & 15;
  const float l2 = __log2f(1.0f - exp2f(-(float)(5 + h)));

  const u16* kg = kb + (size_t)bh * 131072 + (size_t)c * 128 * 64;
  const u16* vg = vtb + (size_t)bh * 131072 + c * 128;
  const u16* Sg = Sb + ((size_t)bh * 16 + c) * 4096;
#pragma unroll
  for (int rg = 0; rg < 4; ++rg) {
    const int kid = w * 4 + rg;
    const int nsub = kid >> 1, kk = kid & 1;     // k regions (t-tile, d-half)
    gld16(kg + (size_t)(nsub * 16 + l15) * 64 + kk * 32 + quad * 8, &kls[kid * 512]);
    const int jd = kid >> 2, kst = kid & 3;      // v regions (d-tile, t-step)
    gld16(vg + (size_t)(jd * 16 + l15) * 2048 + kst * 32 + quad * 8, &vls[kid * 512]);
  }
#pragma unroll
  for (int e = 0; e < 2; ++e) {
    const int rid = w * 2 + e;                   // S regions (dv-tile, dk-half)
    const int nd = rid >> 1, kk = rid & 1;
    gld16(Sg + (size_t)(nd * 16 + l15) * 64 + kk * 32 + quad * 8, &Sls[rid * 512]);
  }

  // q fragments (global loads, not part of LDS staging)
  short8 qf[2][2];
  {
    const u16* qbase = qb + ((size_t)bh * 2048 + c * 128 + w * 32 + l15) * 64 + quad * 8;
#pragma unroll
    for (int i = 0; i < 2; ++i)
#pragma unroll
      for (int kk = 0; kk < 2; ++kk)
        qf[i][kk] = *(const short8*)(qbase + (size_t)i * 16 * 64 + kk * 32);
  }
  float lnwv[4], lnbv[4];
#pragma unroll
  for (int jd = 0; jd < 4; ++jd) {
    lnwv[jd] = lnw[jd * 16 + l15];
    lnbv[jd] = lnb[jd * 16 + l15];
  }
  __syncthreads();

  // ---- intra scores: S = q k^T (32 s-rows x 128 t-cols)
  floatx4 sacc[2][8] = {};
#pragma unroll
  for (int kk = 0; kk < 2; ++kk) {
    short8 bf[8];
#pragma unroll
    for (int j = 0; j < 8; ++j)
      bf[j] = *(const short8*)&kls[(j * 2 + kk) * 512 + lane * 8];
#pragma unroll
    for (int i = 0; i < 2; ++i)
#pragma unroll
      for (int j = 0; j < 8; ++j)
        sacc[i][j] = mfma16(qf[i][kk], bf[j], sacc[i][j]);
  }

  // ---- cross: oacc = q . S_state^T, scaled by lambda^{s_loc+1}
  floatx4 oacc[2][4] = {};
#pragma unroll
  for (int kk = 0; kk < 2; ++kk)
#pragma unroll
    for (int nd = 0; nd < 4; ++nd) {
      short8 sf = *(const short8*)&Sls[(nd * 2 + kk) * 512 + lane * 8];
#pragma unroll
      for (int i = 0; i < 2; ++i)
        oacc[i][nd] = mfma16(qf[i][kk], sf, oacc[i][nd]);
    }
  float rowf[8];
#pragma unroll
  for (int i = 0; i < 2; ++i)
#pragma unroll
    for (int r = 0; r < 4; ++r)
      rowf[i * 4 + r] = exp2f((float)(w * 32 + i * 16 + quad * 4 + r) * l2);
  const float lam1 = exp2f(l2);
#pragma unroll
  for (int i = 0; i < 2; ++i)
#pragma unroll
    for (int nd = 0; nd < 4; ++nd)
#pragma unroll
      for (int r = 0; r < 4; ++r)
        oacc[i][nd][r] *= rowf[i * 4 + r] * lam1;   // lambda^{s_loc+1}

  // ---- intra PV with masked/decayed P, quarter-strip at a time
  float colf[8];
#pragma unroll
  for (int j = 0; j < 8; ++j) colf[j] = exp2f(-(float)(j * 16 + l15) * l2);
  u16* pw = &pls[w * 1280];
#pragma unroll
  for (int kst = 0; kst < 4; ++kst) {
#pragma unroll
    for (int jl = 0; jl < 2; ++jl) {
      const int j = kst * 2 + jl;
#pragma unroll
      for (int i = 0; i < 2; ++i)
#pragma unroll
        for (int r = 0; r < 4; ++r) {
          const int srow = i * 16 + quad * 4 + r;            // wave-local s
          const int dlt = (w * 32 + srow) - (j * 16 + l15);  // causal in-chunk
          const float v =
              (dlt >= 0) ? sacc[i][j][r] * rowf[i * 4 + r] * colf[j] : 0.0f;
          pw[srow * 40 + jl * 16 + l15] = f2bf(v);
        }
    }
    short8 pf[2], vf[4];
#pragma unroll
    for (int i = 0; i < 2; ++i)
      pf[i] = *(const short8*)&pw[(i * 16 + l15) * 40 + quad * 8];
#pragma unroll
    for (int jd = 0; jd < 4; ++jd)
      vf[jd] = *(const short8*)&vls[(jd * 4 + kst) * 512 + lane * 8];
#pragma unroll
    for (int i = 0; i < 2; ++i)
#pragma unroll
      for (int jd = 0; jd < 4; ++jd)
        oacc[i][jd] = mfma16(pf[i], vf[jd], oacc[i][jd]);
  }

  // ---- LayerNorm(64) + SiLU -> y bf16 [token][h*64+d]
  const int b = bh >> 4;
#pragma unroll
  for (int i = 0; i < 2; ++i)
#pragma unroll
    for (int r = 0; r < 4; ++r) {
      float sum = 0.f, ssq = 0.f;
#pragma unroll
      for (int jd = 0; jd < 4; ++jd) {
        const float v = oacc[i][jd][r];
        sum += v;
        ssq += v * v;
      }
#pragma unroll
      for (int off = 1; off < 16; off <<= 1) {
        sum += __shfl_xor(sum, off, 64);
        ssq += __shfl_xor(ssq, off, 64);
      }
      const float mu = sum * (1.0f / 64.0f);
      const float var = ssq * (1.0f / 64.0f) - mu * mu;
      const float rst = rsqrtf(var + 1e-5f);
      const int sg = c * 128 + w * 32 + i * 16 + quad * 4 + r;
      u16* dst = yb + ((size_t)b * 2048 + sg) * 1024 + h * 64;
#pragma unroll
      for (int jd = 0; jd < 4; ++jd) {
        const float z = (oacc[i][jd][r] - mu) * rst * lnwv[jd] + lnbv[jd];
        const float y = z / (1.0f + expf(-z));   // SiLU
        dst[jd * 16 + l15] = f2bf(y);
      }
    }
}

// ---------------------------------------------------------------- launch
extern "C" void kernel_launch(void* const* d_in, const int* in_sizes, int n_in,
                              void* d_out, int out_size, void* d_ws, size_t ws_size,
                              hipStream_t stream) {
  const float* x   = (const float*)d_in[0];
  const float* Wq  = (const float*)d_in[1];
  const float* Wk  = (const float*)d_in[2];
  const float* Wv  = (const float*)d_in[3];
  const float* Wo  = (const float*)d_in[4];
  const float* lnw = (const float*)d_in[5];
  const float* lnb = (const float*)d_in[6];
  float* out = (float*)d_out;

  char* ws = (char*)d_ws;
  u16* xbf  = (u16*)(ws + 0);         // 16 MB (8192x1024 bf16), reused as y
  u16* wqkv = (u16*)(ws + 16777216);  // 6 MB — dead after QKV gemm
  u16* Sb   = (u16*)(ws + 16777216);  // 8 MB S^T states — written after wqkv dead
  u16* qbuf = (u16*)(ws + 25165824);  // 16 MB [bh][s][64]
  u16* kbuf = (u16*)(ws + 41943040);  // 16 MB [bh][s][64]
  u16* vtb  = (u16*)(ws + 58720256);  // 16 MB [bh][64][s]
  u16* wo   = (u16*)(ws + 75497472);  // 2 MB
  float2* rtab = (float2*)(ws + 77594624);  // 512 KB
  u16* yb   = xbf;
  // d_out doubles as scratch until the final GEMM overwrites it entirely:
  u16* kwt  = (u16*)d_out;                          // 16 MB [bh][dk][t] weighted k^T
  float* Ubuf = (float*)((char*)d_out + 16777216);  // 16 MB fp32 chunk outer products

  prep_kernel<<<dim3(1024), dim3(256), 0, stream>>>(x, Wq, Wk, Wv, Wo, xbf, wqkv, wo,
                                                    rtab);
  gemm_bt<0><<<dim3(24, 64), dim3(256), 0, stream>>>(xbf, wqkv, 1024, qbuf, kbuf, vtb,
                                                     kwt, rtab, nullptr);
  kvchunk_kernel<<<dim3(16, 64), dim3(256), 0, stream>>>(kwt, vtb, Ubuf);
  scan_kernel<<<dim3(64), dim3(256), 0, stream>>>(Ubuf, Sb);
  attn_chunk_kernel<<<dim3(16, 64), dim3(256), 0, stream>>>(qbuf, kbuf, vtb, Sb, lnw,
                                                            lnb, yb);
  gemm_bt<1><<<dim3(8, 64), dim3(256), 0, stream>>>(yb, wo, 1024, nullptr, nullptr,
                                                    nullptr, nullptr, nullptr, out);
}

// Round 11
// 308.282 us; speedup vs baseline: 1.0996x; 1.0237x over previous
//
#include <hip/hip_runtime.h>
#include <math.h>

typedef unsigned short u16;
typedef __attribute__((ext_vector_type(8))) short short8;   // 8 bf16 operand frag (4 VGPRs)
typedef __attribute__((ext_vector_type(4))) float floatx4;  // 4 fp32 accum frag

#define LDS_AS(p) ((__attribute__((address_space(3))) void*)(p))
#define GLB_AS(p) ((const __attribute__((address_space(1))) void*)(p))

__device__ __forceinline__ u16 f2bf(float f) {
  unsigned int u = __float_as_uint(f);
  u += 0x7fffu + ((u >> 16) & 1u);          // round-to-nearest-even
  return (u16)(u >> 16);
}

__device__ __forceinline__ void gld16(const void* g, void* l) {
  // async global->LDS, 16B/lane, dest = wave-uniform base + lane*16
  __builtin_amdgcn_global_load_lds(GLB_AS(g), LDS_AS(l), 16, 0, 0);
}

__device__ __forceinline__ floatx4 mfma16(short8 a, short8 b, floatx4 c) {
  return __builtin_amdgcn_mfma_f32_16x16x32_bf16(a, b, c, 0, 0, 0);
}

// ---------------------------------------------------------------- fused prep
__global__ void prep_kernel(const float* __restrict__ x, const float* __restrict__ Wq,
                            const float* __restrict__ Wk, const float* __restrict__ Wv,
                            const float* __restrict__ Wo, u16* __restrict__ xbf,
                            u16* __restrict__ wqkv, u16* __restrict__ wo,
                            float2* __restrict__ rtab) {
  int i = blockIdx.x * blockDim.x + threadIdx.x;
  const int str = gridDim.x * blockDim.x;
  for (; i < 3211264; i += str) {
    if (i < 3145728) {
      const float* s; u16* d; int j;
      if (i < 2097152)      { s = x;  d = xbf;            j = i; }
      else if (i < 2359296) { s = Wq; d = wqkv;           j = i - 2097152; }
      else if (i < 2621440) { s = Wk; d = wqkv + 1048576; j = i - 2359296; }
      else if (i < 2883584) { s = Wv; d = wqkv + 2097152; j = i - 2621440; }
      else                  { s = Wo; d = wo;             j = i - 2883584; }
      float4 v = ((const float4*)s)[j];
      ushort4 o;
      o.x = f2bf(v.x); o.y = f2bf(v.y); o.z = f2bf(v.z); o.w = f2bf(v.w);
      ((ushort4*)d)[j] = o;
    } else {
      const int t = i - 3145728;              // 0..65535
      const int seq = t >> 5, dh = t & 31;
      const float freq = exp2f(-(float)dh * 0.42863594770f); // log2(1e4)/31
      float sn, cs;
      __sincosf((float)seq * freq, &sn, &cs);
      rtab[t] = make_float2(sn, cs);
    }
  }
}

// ---------------------------------------------------------------- GEMM C = A * B^T
// 128x128 tile, BK=64, fragment-ordered LDS K-loop. NATURAL block mapping
// (round-10's XCD swizzle regressed the QKV gemm 133->143 us: it broke the
// A-slab sharing between consecutively-dispatched blocks).
// Epilogue staged via LDS with CHUNK ROTATION to break the 8-way bank
// conflicts (4.46M/dispatch at r8-r10): pass-1 scalar writes rotate the
// d-chunk by (sl>>2); transpose passes rotate the seq position by 8*(d&7).
// Readback inverts the rotation on the chunk index only (short8 stays
// contiguous). Worst case 8-way -> 4-way (~1.58x, near-free per m136).
template <int EPI>
__global__ __launch_bounds__(256, 2)
void gemm_bt(const u16* __restrict__ A, const u16* __restrict__ Bw, int K,
             u16* __restrict__ qb, u16* __restrict__ kb, u16* __restrict__ vtb,
             u16* __restrict__ kwt, const float2* __restrict__ rtab,
             float* __restrict__ outp) {
  __shared__ __align__(16) u16 Asm[16 * 512];   // 8 row-tiles x 2 k-halves
  __shared__ __align__(16) u16 Bsm[16 * 512];
  const int tid = threadIdx.x;
  const int w = tid >> 6, lane = tid & 63;
  const int quad = lane >> 4, l15 = lane & 15;
  const int m0 = blockIdx.y * 128, n0 = blockIdx.x * 128;

  // staging: wave w stages A row-tiles {2w,2w+1}, both 32-wide k-halves
  const u16* Ag = A + (size_t)(m0 + (2 * w) * 16 + l15) * K + quad * 8;
  const u16* Bg = Bw + (size_t)(n0 + (2 * w) * 16 + l15) * K + quad * 8;
  const size_t row16 = (size_t)16 * K;

  const u16* Apane = &Asm[(w & 1) * 8 * 512];   // 4 row-tiles x 2 kk
  const u16* Bpane = &Bsm[(w >> 1) * 8 * 512];

  floatx4 acc[4][4] = {};

  for (int k0 = 0; k0 < K; k0 += 64) {
#pragma unroll
    for (int rt = 0; rt < 2; ++rt)
#pragma unroll
      for (int kk = 0; kk < 2; ++kk) {
        gld16(Ag + rt * row16 + k0 + kk * 32, &Asm[((2 * w + rt) * 2 + kk) * 512]);
        gld16(Bg + rt * row16 + k0 + kk * 32, &Bsm[((2 * w + rt) * 2 + kk) * 512]);
      }
    __syncthreads();   // drains vmcnt: staging complete
#pragma unroll
    for (int kk = 0; kk < 2; ++kk) {
      short8 a[4], b[4];
#pragma unroll
      for (int i = 0; i < 4; ++i)
        a[i] = *(const short8*)&Apane[(i * 2 + kk) * 512 + lane * 8];
#pragma unroll
      for (int j = 0; j < 4; ++j)
        b[j] = *(const short8*)&Bpane[(j * 2 + kk) * 512 + lane * 8];
#pragma unroll
      for (int i = 0; i < 4; ++i)
#pragma unroll
        for (int j = 0; j < 4; ++j)
          acc[i][j] = mfma16(a[i], b[j], acc[i][j]);
    }
    __syncthreads();   // all waves done reading before next stage overwrites
  }
  // after the final barrier Asm/Bsm are dead -> 8 KB wave-private scratch
  u16* scr = (w < 2 ? Asm : Bsm) + (w & 1) * 4096;

  const int mrb = m0 + (w & 1) * 64;
  const int ncb = n0 + (w >> 1) * 64;

  if (EPI == 0) {
    const int which = n0 >> 10;       // 0:q 1:k 2:v
    const int c1024 = ncb & 1023;
    const int bidx = mrb >> 11;
    const int hh = c1024 >> 6;        // wave-tile = one full head (64 d)
    const int seq0 = mrb & 2047;
    const int lr = lane >> 3, lc = lane & 7;   // readback row-group / 16B chunk

    if (which < 2) {
      // ---- pass 1: plain q/k [bh][s][64], RoPE applied. Rotated d-chunks.
#pragma unroll
      for (int j = 0; j < 4; ++j) {
        const int d = j * 16 + l15;
        const int dc = d >> 3, dl = d & 7;
#pragma unroll
        for (int i = 0; i < 4; ++i)
#pragma unroll
          for (int r = 0; r < 4; ++r) {
            const int sl = i * 16 + quad * 4 + r;
            const int seq = seq0 + sl;
            const float v = acc[i][j][r];
            const float p = __shfl_xor(v, 1, 64);
            const float2 sc = rtab[(d >> 1) + seq * 32];
            const float res = (d & 1) ? (v * sc.y + p * sc.x) : (v * sc.y - p * sc.x);
            scr[sl * 64 + (((dc + (sl >> 2)) & 7) << 3) + dl] = f2bf(res);
          }
      }
      u16* dst = ((which == 0) ? qb : kb) + (size_t)(bidx * 16 + hh) * 131072 +
                 (size_t)seq0 * 64;
#pragma unroll
      for (int cch = 0; cch < 8; ++cch) {        // 8 stores, full 128B segments
        const int row = cch * 8 + lr;
        const int slot = (lc + (row >> 2)) & 7;
        short8 vv = *(const short8*)&scr[row * 64 + slot * 8];
        *(short8*)(dst + (size_t)row * 64 + lc * 8) = vv;
      }
      if (which == 1) {
        // ---- pass 2: kwt [bh][dk][t], decay-weighted, transposed, rotated
        const float l2h = __log2f(1.0f - exp2f(-(float)(5 + hh)));
#pragma unroll
        for (int j = 0; j < 4; ++j) {
          const int d = j * 16 + l15;
#pragma unroll
          for (int i = 0; i < 4; ++i) {
            ushort4 pk;
#pragma unroll
            for (int r = 0; r < 4; ++r) {
              const int sl = i * 16 + quad * 4 + r;
              const int seq = seq0 + sl;
              const float v = acc[i][j][r];
              const float p = __shfl_xor(v, 1, 64);
              const float2 sc = rtab[(d >> 1) + seq * 32];
              const float res = (d & 1) ? (v * sc.y + p * sc.x) : (v * sc.y - p * sc.x);
              const float wgt = exp2f((float)(127 - (seq & 127)) * l2h);
              ((u16*)&pk)[r] = f2bf(res * wgt);
            }
            *(ushort4*)&scr[d * 64 + ((i * 16 + quad * 4 + 8 * (d & 7)) & 63)] = pk;
          }
        }
        u16* dw = kwt + (size_t)(bidx * 16 + hh) * 131072 + seq0;
#pragma unroll
        for (int cch = 0; cch < 8; ++cch) {
          const int drow = cch * 8 + lr;
          const int slot = (lc + (drow & 7)) & 7;
          short8 vv = *(const short8*)&scr[drow * 64 + slot * 8];
          *(short8*)(dw + (size_t)drow * 2048 + lc * 8) = vv;
        }
      }
    } else {
      // ---- v transposed [bh][d][s] via LDS, rotated seq-chunks
#pragma unroll
      for (int j = 0; j < 4; ++j) {
        const int d = j * 16 + l15;
#pragma unroll
        for (int i = 0; i < 4; ++i) {
          ushort4 pk;
          pk.x = f2bf(acc[i][j][0]);
          pk.y = f2bf(acc[i][j][1]);
          pk.z = f2bf(acc[i][j][2]);
          pk.w = f2bf(acc[i][j][3]);
          *(ushort4*)&scr[d * 64 + ((i * 16 + quad * 4 + 8 * (d & 7)) & 63)] = pk;
        }
      }
      u16* dh = vtb + (size_t)(bidx * 16 + hh) * 131072 + seq0;
#pragma unroll
      for (int cch = 0; cch < 8; ++cch) {
        const int drow = cch * 8 + lr;
        const int slot = (lc + (drow & 7)) & 7;
        short8 vv = *(const short8*)&scr[drow * 64 + slot * 8];
        *(short8*)(dh + (size_t)drow * 2048 + lc * 8) = vv;
      }
    }
  } else {
    // ---- fp32 out via LDS quarter-tiles (16 rows x pitch 65), full-line stores
    float* scrf = (float*)scr;                  // 8 KB = 2048 fp32
    const int lr4 = lane >> 4, lc16 = lane & 15;
#pragma unroll
    for (int p = 0; p < 4; ++p) {               // p = row-group (acc i index)
#pragma unroll
      for (int j = 0; j < 4; ++j)
#pragma unroll
        for (int r = 0; r < 4; ++r)
          scrf[(quad * 4 + r) * 65 + j * 16 + l15] = acc[p][j][r];
#pragma unroll
      for (int cch = 0; cch < 4; ++cch) {       // 4 stores x 4 rows x 256 B
        const int rr = cch * 4 + lr4;
        float4 vv = *(const float4*)&scrf[rr * 65 + lc16 * 4];
        *(float4*)&outp[(size_t)(mrb + p * 16 + rr) * 1024 + ncb + lc16 * 4] = vv;
      }
    }
  }
}

// ---------------------------------------------------------------- chunk KV: U_c = sum_t w_t k_t v_t^T
__global__ __launch_bounds__(256, 4)
void kvchunk_kernel(const u16* __restrict__ kwt, const u16* __restrict__ vtb,
                    float* __restrict__ U) {
  __shared__ __align__(16) u16 kls[16 * 512];
  __shared__ __align__(16) u16 vls[16 * 512];
  const int c = blockIdx.x, bh = blockIdx.y;
  const int tid = threadIdx.x, w = tid >> 6, lane = tid & 63;
  const int quad = lane >> 4, l15 = lane & 15;
  const u16* kg = kwt + (size_t)bh * 131072 + c * 128;
  const u16* vg = vtb + (size_t)bh * 131072 + c * 128;
#pragma unroll
  for (int rg = 0; rg < 4; ++rg) {
    const int rid = w * 4 + rg;               // 16 regions: (tile m, kst)
    const int m = rid >> 2, kst = rid & 3;
    gld16(kg + (size_t)(m * 16 + l15) * 2048 + kst * 32 + quad * 8, &kls[rid * 512]);
    gld16(vg + (size_t)(m * 16 + l15) * 2048 + kst * 32 + quad * 8, &vls[rid * 512]);
  }
  __syncthreads();
  floatx4 acc[4] = {};
#pragma unroll
  for (int kst = 0; kst < 4; ++kst) {
    short8 bf = *(const short8*)&vls[(w * 4 + kst) * 512 + lane * 8];
#pragma unroll
    for (int m = 0; m < 4; ++m) {
      short8 af = *(const short8*)&kls[(m * 4 + kst) * 512 + lane * 8];
      acc[m] = mfma16(af, bf, acc[m]);
    }
  }
  float* Ub = U + ((size_t)bh * 16 + c) * 4096;
#pragma unroll
  for (int m = 0; m < 4; ++m)
#pragma unroll
    for (int r = 0; r < 4; ++r)
      Ub[(m * 16 + quad * 4 + r) * 64 + w * 16 + l15] = acc[m][r];
}

// ---------------------------------------------------------------- state scan
// 64 blocks x 4 waves: wave w owns dk-quarter [w*16, w*16+16), lane = dv.
__global__ void scan_kernel(const float* __restrict__ U, u16* __restrict__ Sb) {
  const int bh = blockIdx.x;
  const int w = threadIdx.x >> 6, l = threadIdx.x & 63;
  const int h = bh & 15;
  const float l2 = __log2f(1.0f - exp2f(-(float)(5 + h)));
  const float lamL = exp2f(128.0f * l2);
  float S[16];
#pragma unroll
  for (int i = 0; i < 16; ++i) S[i] = 0.f;
  for (int c = 0; c < 16; ++c) {
    u16* sp = Sb + ((size_t)bh * 16 + c) * 4096 + l * 64 + w * 16;
#pragma unroll
    for (int dk = 0; dk < 16; dk += 4) {
      ushort4 pk;
      pk.x = f2bf(S[dk]);     pk.y = f2bf(S[dk + 1]);
      pk.z = f2bf(S[dk + 2]); pk.w = f2bf(S[dk + 3]);
      *(ushort4*)&sp[dk] = pk;
    }
    const float* up = U + ((size_t)bh * 16 + c) * 4096 + (w * 16) * 64 + l;
#pragma unroll
    for (int dk = 0; dk < 16; ++dk)
      S[dk] = lamL * S[dk] + up[dk * 64];
  }
}

// ---------------------------------------------------------------- chunked attention
__global__ __launch_bounds__(256, 2)
void attn_chunk_kernel(const u16* __restrict__ qb, const u16* __restrict__ kb,
                       const u16* __restrict__ vtb, const u16* __restrict__ Sb,
                       const float* __restrict__ lnw, const float* __restrict__ lnb,
                       u16* __restrict__ yb) {
  __shared__ __align__(16) u16 kls[16 * 512];
  __shared__ __align__(16) u16 vls[16 * 512];
  __shared__ __align__(16) u16 Sls[8 * 512];
  __shared__ __align__(16) u16 pls[4 * 32 * 40];   // per-wave quarter P strip, pitch 40

  const int c = blockIdx.x, bh = blockIdx.y, h = bh & 15;
  const int tid = threadIdx.x;
  const int w = tid >> 6, lane = tid & 63, quad = lane >> 4, l15 = lane & 15;
  const float l2 = __log2f(1.0f - exp2f(-(float)(5 + h)));

  const u16* kg = kb + (size_t)bh * 131072 + (size_t)c * 128 * 64;
  const u16* vg = vtb + (size_t)bh * 131072 + c * 128;
  const u16* Sg = Sb + ((size_t)bh * 16 + c) * 4096;
#pragma unroll
  for (int rg = 0; rg < 4; ++rg) {
    const int kid = w * 4 + rg;
    const int nsub = kid >> 1, kk = kid & 1;     // k regions (t-tile, d-half)
    gld16(kg + (size_t)(nsub * 16 + l15) * 64 + kk * 32 + quad * 8, &kls[kid * 512]);
    const int jd = kid >> 2, kst = kid & 3;      // v regions (d-tile, t-step)
    gld16(vg + (size_t)(jd * 16 + l15) * 2048 + kst * 32 + quad * 8, &vls[kid * 512]);
  }
#pragma unroll
  for (int e = 0; e < 2; ++e) {
    const int rid = w * 2 + e;                   // S regions (dv-tile, dk-half)
    const int nd = rid >> 1, kk = rid & 1;
    gld16(Sg + (size_t)(nd * 16 + l15) * 64 + kk * 32 + quad * 8, &Sls[rid * 512]);
  }

  // q fragments (global loads, not part of LDS staging)
  short8 qf[2][2];
  {
    const u16* qbase = qb + ((size_t)bh * 2048 + c * 128 + w * 32 + l15) * 64 + quad * 8;
#pragma unroll
    for (int i = 0; i < 2; ++i)
#pragma unroll
      for (int kk = 0; kk < 2; ++kk)
        qf[i][kk] = *(const short8*)(qbase + (size_t)i * 16 * 64 + kk * 32);
  }
  float lnwv[4], lnbv[4];
#pragma unroll
  for (int jd = 0; jd < 4; ++jd) {
    lnwv[jd] = lnw[jd * 16 + l15];
    lnbv[jd] = lnb[jd * 16 + l15];
  }
  __syncthreads();

  // ---- intra scores: S = q k^T (32 s-rows x 128 t-cols)
  floatx4 sacc[2][8] = {};
#pragma unroll
  for (int kk = 0; kk < 2; ++kk) {
    short8 bf[8];
#pragma unroll
    for (int j = 0; j < 8; ++j)
      bf[j] = *(const short8*)&kls[(j * 2 + kk) * 512 + lane * 8];
#pragma unroll
    for (int i = 0; i < 2; ++i)
#pragma unroll
      for (int j = 0; j < 8; ++j)
        sacc[i][j] = mfma16(qf[i][kk], bf[j], sacc[i][j]);
  }

  // ---- cross: oacc = q . S_state^T, scaled by lambda^{s_loc+1}
  floatx4 oacc[2][4] = {};
#pragma unroll
  for (int kk = 0; kk < 2; ++kk)
#pragma unroll
    for (int nd = 0; nd < 4; ++nd) {
      short8 sf = *(const short8*)&Sls[(nd * 2 + kk) * 512 + lane * 8];
#pragma unroll
      for (int i = 0; i < 2; ++i)
        oacc[i][nd] = mfma16(qf[i][kk], sf, oacc[i][nd]);
    }
  float rowf[8];
#pragma unroll
  for (int i = 0; i < 2; ++i)
#pragma unroll
    for (int r = 0; r < 4; ++r)
      rowf[i * 4 + r] = exp2f((float)(w * 32 + i * 16 + quad * 4 + r) * l2);
  const float lam1 = exp2f(l2);
#pragma unroll
  for (int i = 0; i < 2; ++i)
#pragma unroll
    for (int nd = 0; nd < 4; ++nd)
#pragma unroll
      for (int r = 0; r < 4; ++r)
        oacc[i][nd][r] *= rowf[i * 4 + r] * lam1;   // lambda^{s_loc+1}

  // ---- intra PV with masked/decayed P, quarter-strip at a time
  float colf[8];
#pragma unroll
  for (int j = 0; j < 8; ++j) colf[j] = exp2f(-(float)(j * 16 + l15) * l2);
  u16* pw = &pls[w * 1280];
#pragma unroll
  for (int kst = 0; kst < 4; ++kst) {
#pragma unroll
    for (int jl = 0; jl < 2; ++jl) {
      const int j = kst * 2 + jl;
#pragma unroll
      for (int i = 0; i < 2; ++i)
#pragma unroll
        for (int r = 0; r < 4; ++r) {
          const int srow = i * 16 + quad * 4 + r;            // wave-local s
          const int dlt = (w * 32 + srow) - (j * 16 + l15);  // causal in-chunk
          const float v =
              (dlt >= 0) ? sacc[i][j][r] * rowf[i * 4 + r] * colf[j] : 0.0f;
          pw[srow * 40 + jl * 16 + l15] = f2bf(v);
        }
    }
    short8 pf[2], vf[4];
#pragma unroll
    for (int i = 0; i < 2; ++i)
      pf[i] = *(const short8*)&pw[(i * 16 + l15) * 40 + quad * 8];
#pragma unroll
    for (int jd = 0; jd < 4; ++jd)
      vf[jd] = *(const short8*)&vls[(jd * 4 + kst) * 512 + lane * 8];
#pragma unroll
    for (int i = 0; i < 2; ++i)
#pragma unroll
      for (int jd = 0; jd < 4; ++jd)
        oacc[i][jd] = mfma16(pf[i], vf[jd], oacc[i][jd]);
  }

  // ---- LayerNorm(64) + SiLU -> y bf16 [token][h*64+d]
  const int b = bh >> 4;
#pragma unroll
  for (int i = 0; i < 2; ++i)
#pragma unroll
    for (int r = 0; r < 4; ++r) {
      float sum = 0.f, ssq = 0.f;
#pragma unroll
      for (int jd = 0; jd < 4; ++jd) {
        const float v = oacc[i][jd][r];
        sum += v;
        ssq += v * v;
      }
#pragma unroll
      for (int off = 1; off < 16; off <<= 1) {
        sum += __shfl_xor(sum, off, 64);
        ssq += __shfl_xor(ssq, off, 64);
      }
      const float mu = sum * (1.0f / 64.0f);
      const float var = ssq * (1.0f / 64.0f) - mu * mu;
      const float rst = rsqrtf(var + 1e-5f);
      const int sg = c * 128 + w * 32 + i * 16 + quad * 4 + r;
      u16* dst = yb + ((size_t)b * 2048 + sg) * 1024 + h * 64;
#pragma unroll
      for (int jd = 0; jd < 4; ++jd) {
        const float z = (oacc[i][jd][r] - mu) * rst * lnwv[jd] + lnbv[jd];
        const float y = z / (1.0f + expf(-z));   // SiLU
        dst[jd * 16 + l15] = f2bf(y);
      }
    }
}

// ---------------------------------------------------------------- launch
extern "C" void kernel_launch(void* const* d_in, const int* in_sizes, int n_in,
                              void* d_out, int out_size, void* d_ws, size_t ws_size,
                              hipStream_t stream) {
  const float* x   = (const float*)d_in[0];
  const float* Wq  = (const float*)d_in[1];
  const float* Wk  = (const float*)d_in[2];
  const float* Wv  = (const float*)d_in[3];
  const float* Wo  = (const float*)d_in[4];
  const float* lnw = (const float*)d_in[5];
  const float* lnb = (const float*)d_in[6];
  float* out = (float*)d_out;

  char* ws = (char*)d_ws;
  u16* xbf  = (u16*)(ws + 0);         // 16 MB (8192x1024 bf16), reused as y
  u16* wqkv = (u16*)(ws + 16777216);  // 6 MB — dead after QKV gemm
  u16* Sb   = (u16*)(ws + 16777216);  // 8 MB S^T states — written after wqkv dead
  u16* qbuf = (u16*)(ws + 25165824);  // 16 MB [bh][s][64]
  u16* kbuf = (u16*)(ws + 41943040);  // 16 MB [bh][s][64]
  u16* vtb  = (u16*)(ws + 58720256);  // 16 MB [bh][64][s]
  u16* wo   = (u16*)(ws + 75497472);  // 2 MB
  float2* rtab = (float2*)(ws + 77594624);  // 512 KB
  u16* yb   = xbf;
  // d_out doubles as scratch until the final GEMM overwrites it entirely:
  u16* kwt  = (u16*)d_out;                          // 16 MB [bh][dk][t] weighted k^T
  float* Ubuf = (float*)((char*)d_out + 16777216);  // 16 MB fp32 chunk outer products

  prep_kernel<<<dim3(1024), dim3(256), 0, stream>>>(x, Wq, Wk, Wv, Wo, xbf, wqkv, wo,
                                                    rtab);
  gemm_bt<0><<<dim3(24, 64), dim3(256), 0, stream>>>(xbf, wqkv, 1024, qbuf, kbuf, vtb,
                                                     kwt, rtab, nullptr);
  kvchunk_kernel<<<dim3(16, 64), dim3(256), 0, stream>>>(kwt, vtb, Ubuf);
  scan_kernel<<<dim3(64), dim3(256), 0, stream>>>(Ubuf, Sb);
  attn_chunk_kernel<<<dim3(16, 64), dim3(256), 0, stream>>>(qbuf, kbuf, vtb, Sb, lnw,
                                                            lnb, yb);
  gemm_bt<1><<<dim3(8, 64), dim3(256), 0, stream>>>(yb, wo, 1024, nullptr, nullptr,
                                                    nullptr, nullptr, nullptr, out);
}